// Round 1
// baseline (1767.303 us; speedup 1.0000x reference)
//
#include <hip/hip_runtime.h>

#define NN 100000
#define NE 1600000
#define INC 128
#define EC 32
#define NH 4
#define CH 32
#define HC 128
#define NEG 0.2f

// workspace layout, in float units
#define OFF_XL    ((size_t)0)            // NN*HC = 12,800,000
#define OFF_AL    ((size_t)12800000)     // NN*NH = 400,000
#define OFF_AR    ((size_t)13200000)     // 400,000
#define OFF_WE    ((size_t)13600000)     // 128
#define OFF_ALPHA ((size_t)13600128)     // NE*NH = 6,400,000 (reused in-place as ex)
#define OFF_AMAX  ((size_t)20000128)     // NN*NH (as flipped uint)
#define OFF_DEN   ((size_t)20400128)     // NN*NH
// total 20,800,128 floats = 83.2 MB

__device__ __forceinline__ unsigned flip_f(float f) {
    unsigned u = __float_as_uint(f);
    unsigned m = (unsigned)(-(int)(u >> 31)) | 0x80000000u;
    return u ^ m;
}
__device__ __forceinline__ float unflip_f(unsigned g) {
    unsigned u = (g & 0x80000000u) ? (g ^ 0x80000000u) : ~g;
    return __uint_as_float(u);
}

// fold att_e into We: we[h*32+k] = sum_c att_e[h*32+c] * We[(h*32+c)*32+k]
__global__ void k_prep(const float* __restrict__ We, const float* __restrict__ att_e,
                       float* __restrict__ we) {
    int t = threadIdx.x;            // 0..127 -> h*32+k
    int h = t >> 5, k = t & 31;
    float s = 0.f;
    for (int c = 0; c < 32; ++c)
        s += att_e[h * 32 + c] * We[(size_t)(h * 32 + c) * 32 + k];
    we[t] = s;
}

// out = bias broadcast; amax = 0 (flipped-uint -inf-ish floor); denom = 0
__global__ void k_init(const float* __restrict__ bias, float* __restrict__ out,
                       unsigned* __restrict__ amax, float* __restrict__ den) {
    size_t i = (size_t)blockIdx.x * 256 + threadIdx.x;   // grid sized to NN*HC exactly
    out[i] = bias[i & 127];
    if (i < (size_t)NN * NH) { amax[i] = 0u; den[i] = 0.f; }
}

// xl = x @ Wl.T ; alpha_l/r = (xl * att)_per-head-sum. 32 nodes/block, 4 at a time.
__global__ __launch_bounds__(128, 2) void k_node(
        const float* __restrict__ x, const float* __restrict__ Wl,
        const float* __restrict__ attl, const float* __restrict__ attr_,
        float* __restrict__ xl, float* __restrict__ al, float* __restrict__ ar) {
    __shared__ float wT[128 * 129];          // wT[k*129+o] = Wl[o*128+k]
    __shared__ __align__(16) float xst[128 * 4]; // xst[k*4+j] = x[n0+j][k]
    int tid = threadIdx.x;

    for (int r = 0; r < 128; ++r)            // coalesced global, conflict-free LDS
        wT[tid * 129 + r] = Wl[(size_t)r * 128 + tid];
    float attl_r = attl[tid], attr_r = attr_[tid];
    __syncthreads();

    int n0 = blockIdx.x * 32;
    for (int g = 0; g < 8; ++g) {
        int nb = n0 + g * 4;
        __syncthreads();
        #pragma unroll
        for (int j = 0; j < 4; ++j)
            xst[tid * 4 + j] = x[(size_t)(nb + j) * 128 + tid];
        __syncthreads();

        float acc[4] = {0.f, 0.f, 0.f, 0.f};
        #pragma unroll 8
        for (int k = 0; k < 128; ++k) {
            float4 xv = *(const float4*)&xst[k * 4];
            float w = wT[k * 129 + tid];
            acc[0] += xv.x * w; acc[1] += xv.y * w;
            acc[2] += xv.z * w; acc[3] += xv.w * w;
        }
        #pragma unroll
        for (int j = 0; j < 4; ++j) {
            xl[(size_t)(nb + j) * 128 + tid] = acc[j];
            float pl = acc[j] * attl_r, pr = acc[j] * attr_r;
            #pragma unroll
            for (int off = 16; off >= 1; off >>= 1) {   // xor<32 stays in 32-lane head group
                pl += __shfl_xor(pl, off);
                pr += __shfl_xor(pr, off);
            }
            if ((tid & 31) == 0) {
                al[(size_t)(nb + j) * 4 + (tid >> 5)] = pl;
                ar[(size_t)(nb + j) * 4 + (tid >> 5)] = pr;
            }
        }
    }
}

// per-edge logits: alpha = leaky(al[src]+ar[dst]+edge_attr·we); atomicMax amax[dst]
__global__ __launch_bounds__(256) void k_edge1(
        const float* __restrict__ eattr, const int* __restrict__ ei,
        const float* __restrict__ al, const float* __restrict__ ar,
        const float* __restrict__ we, float* __restrict__ alpha,
        unsigned* __restrict__ amax) {
    __shared__ __align__(16) float wsh[128];
    if (threadIdx.x < 128) wsh[threadIdx.x] = we[threadIdx.x];
    __syncthreads();
    int e = blockIdx.x * 256 + threadIdx.x;   // grid sized exactly
    int src = ei[e], dst = ei[NE + e];
    const float4* ea = (const float4*)(eattr + (size_t)e * 32);
    float a[4] = {0.f, 0.f, 0.f, 0.f};
    #pragma unroll
    for (int r = 0; r < 8; ++r) {
        float4 v = ea[r];
        #pragma unroll
        for (int h = 0; h < 4; ++h) {
            float4 w = *(const float4*)&wsh[h * 32 + r * 4];
            a[h] += v.x * w.x + v.y * w.y + v.z * w.z + v.w * w.w;
        }
    }
    float4 ls = *(const float4*)&al[(size_t)src * 4];
    float4 rs = *(const float4*)&ar[(size_t)dst * 4];
    a[0] += ls.x + rs.x; a[1] += ls.y + rs.y;
    a[2] += ls.z + rs.z; a[3] += ls.w + rs.w;
    #pragma unroll
    for (int h = 0; h < 4; ++h) a[h] = a[h] > 0.f ? a[h] : NEG * a[h];
    *(float4*)&alpha[(size_t)e * 4] = make_float4(a[0], a[1], a[2], a[3]);
    #pragma unroll
    for (int h = 0; h < 4; ++h)
        atomicMax(&amax[(size_t)dst * 4 + h], flip_f(a[h]));
}

// ex = exp(alpha - amax[dst]) in-place; atomicAdd denom[dst]
__global__ __launch_bounds__(256) void k_edge2(
        const int* __restrict__ ei, float* __restrict__ alpha,
        const unsigned* __restrict__ amax, float* __restrict__ den) {
    int e = blockIdx.x * 256 + threadIdx.x;
    int dst = ei[NE + e];
    float4 a = *(const float4*)&alpha[(size_t)e * 4];
    uint4 g = *(const uint4*)&amax[(size_t)dst * 4];
    float ex[4];
    ex[0] = __expf(a.x - unflip_f(g.x));
    ex[1] = __expf(a.y - unflip_f(g.y));
    ex[2] = __expf(a.z - unflip_f(g.z));
    ex[3] = __expf(a.w - unflip_f(g.w));
    *(float4*)&alpha[(size_t)e * 4] = make_float4(ex[0], ex[1], ex[2], ex[3]);
    #pragma unroll
    for (int h = 0; h < 4; ++h)
        atomicAdd(&den[(size_t)dst * 4 + h], ex[h]);
}

// out[dst,:] += xl[src,:] * ex/(den[dst]+eps); 2 edges per 256-thread block
__global__ __launch_bounds__(256) void k_edge3(
        const int* __restrict__ ei, const float* __restrict__ alpha,
        const float* __restrict__ den, const float* __restrict__ xl,
        float* __restrict__ out) {
    size_t t = (size_t)blockIdx.x * 256 + threadIdx.x;
    int e = (int)(t >> 7);
    int j = (int)(t & 127);
    int h = j >> 5;
    int src = ei[e], dst = ei[NE + e];
    float w = alpha[(size_t)e * 4 + h] / (den[(size_t)dst * 4 + h] + 1e-16f);
    float val = xl[(size_t)src * 128 + j] * w;
    atomicAdd(&out[(size_t)dst * 128 + j], val);
}

extern "C" void kernel_launch(void* const* d_in, const int* in_sizes, int n_in,
                              void* d_out, int out_size, void* d_ws, size_t ws_size,
                              hipStream_t stream) {
    const float* x     = (const float*)d_in[0];
    const float* eattr = (const float*)d_in[1];
    const float* Wl    = (const float*)d_in[2];
    const float* We    = (const float*)d_in[3];
    const float* att_l = (const float*)d_in[4];
    const float* att_r = (const float*)d_in[5];
    const float* att_e = (const float*)d_in[6];
    const float* bias  = (const float*)d_in[7];
    const int*   ei    = (const int*)d_in[8];
    float* out = (float*)d_out;

    float* ws = (float*)d_ws;
    float*    xl    = ws + OFF_XL;
    float*    al    = ws + OFF_AL;
    float*    ar    = ws + OFF_AR;
    float*    we    = ws + OFF_WE;
    float*    alpha = ws + OFF_ALPHA;
    unsigned* amax  = (unsigned*)(ws + OFF_AMAX);
    float*    den   = ws + OFF_DEN;

    k_prep<<<1, 128, 0, stream>>>(We, att_e, we);
    k_init<<<(NN * HC) / 256, 256, 0, stream>>>(bias, out, amax, den);
    k_node<<<NN / 32, 128, 0, stream>>>(x, Wl, att_l, att_r, xl, al, ar);
    k_edge1<<<NE / 256, 256, 0, stream>>>(eattr, ei, al, ar, we, alpha, amax);
    k_edge2<<<NE / 256, 256, 0, stream>>>(ei, alpha, amax, den);
    k_edge3<<<(size_t)NE * 128 / 256, 256, 0, stream>>>(ei, alpha, den, xl, out);
}

// Round 3
// 803.495 us; speedup vs baseline: 2.1995x; 2.1995x over previous
//
#include <hip/hip_runtime.h>

#define NN 100000
#define NE 1600000
#define NB 391            // ceil(NN/256)
#define NEG 0.2f

// workspace layout (4-byte units)
#define OFF_XL    ((size_t)0)            // NN*128 = 12,800,000 f
#define OFF_AL    ((size_t)12800000)     // NN*4 f
#define OFF_AR    ((size_t)13200000)     // NN*4 f
#define OFF_WE    ((size_t)13600000)     // 128 f
#define OFF_ALPHA ((size_t)13600128)     // NE*4 f (dst-sorted)
#define OFF_SRC   ((size_t)20000128)     // NE int (dst-sorted src); TMP/BSUM alias here pre-scatter
#define OFF_TMP   OFF_SRC                // NN int  (dead before k_scatter writes SRC)
#define OFF_BSUM  (OFF_SRC + 110000)     // 512 int (dead before k_scatter)
#define OFF_DEG   ((size_t)21600128)     // NN int (deg, then cursor)
#define OFF_ROW   ((size_t)21700128)     // NN+1 int
// total ~21,800,129 * 4B = 87.2 MB

// fold att_e into We: we[h*32+k] = sum_c att_e[h*32+c] * We[(h*32+c)*32+k]
__global__ void k_prep(const float* __restrict__ We, const float* __restrict__ att_e,
                       float* __restrict__ we) {
    int t = threadIdx.x;            // 0..127 -> h*32+k
    int h = t >> 5, k = t & 31;
    float s = 0.f;
    for (int c = 0; c < 32; ++c)
        s += att_e[h * 32 + c] * We[(size_t)(h * 32 + c) * 32 + k];
    we[t] = s;
}

__global__ void k_zero(int* __restrict__ deg) {
    int i = blockIdx.x * 256 + threadIdx.x;
    if (i < NN) deg[i] = 0;
}

__global__ void k_hist(const int* __restrict__ ei, int* __restrict__ deg) {
    int e = blockIdx.x * 256 + threadIdx.x;
    atomicAdd(&deg[ei[NE + e]], 1);
}

// ---- node projection GEMM: xl = x @ Wl.T, fused al/ar head-dot reductions ----
// 32 nodes/block, 256 thr = 32 out-groups x 8 node-groups; thread = 4 outs x 4 nodes.
__global__ __launch_bounds__(256, 2) void k_node(
        const float* __restrict__ x, const float* __restrict__ Wl,
        const float* __restrict__ attl, const float* __restrict__ attr_,
        float* __restrict__ xl, float* __restrict__ al, float* __restrict__ ar) {
    __shared__ float wT[128 * 128];   // wT[k*128+o]
    __shared__ float xT[128 * 32];    // xT[k*32+n]
    int t = threadIdx.x;
    int og = t & 31, ng = t >> 5;
    int nb = blockIdx.x * 32;

    // stage Wl transposed: o = t&127 covers ALL 128 output cols (round-2 bug: was t&31).
    // 256 threads x 16 float4 chunks = 16384 elements = full 128x128 tile.
    {
        int o = t & 127, q = t >> 7;              // o 0..127, q 0..1
        #pragma unroll
        for (int chunk = 0; chunk < 16; ++chunk) {
            int k0 = chunk * 8 + q * 4;
            float4 w = *(const float4*)&Wl[(size_t)o * 128 + k0];
            wT[(k0 + 0) * 128 + o] = w.x;
            wT[(k0 + 1) * 128 + o] = w.y;
            wT[(k0 + 2) * 128 + o] = w.z;
            wT[(k0 + 3) * 128 + o] = w.w;
        }
    }
    // stage x tile transposed (n only needs 0..31)
    {
        int n = t & 31, q = t >> 5;               // q 0..7
        #pragma unroll
        for (int chunk = 0; chunk < 4; ++chunk) {
            int k0 = chunk * 32 + q * 4;
            float4 v = *(const float4*)&x[(size_t)(nb + n) * 128 + k0];
            xT[(k0 + 0) * 32 + n] = v.x;
            xT[(k0 + 1) * 32 + n] = v.y;
            xT[(k0 + 2) * 32 + n] = v.z;
            xT[(k0 + 3) * 32 + n] = v.w;
        }
    }
    float4 attl4 = *(const float4*)&attl[og * 4];
    float4 attr4 = *(const float4*)&attr_[og * 4];
    __syncthreads();

    float4 a0 = make_float4(0,0,0,0), a1 = a0, a2 = a0, a3 = a0;
    #pragma unroll 8
    for (int k = 0; k < 128; ++k) {
        float4 w  = *(const float4*)&wT[k * 128 + og * 4];  // contiguous across og
        float4 xv = *(const float4*)&xT[k * 32  + ng * 4];  // broadcast-heavy
        a0.x += w.x * xv.x; a0.y += w.y * xv.x; a0.z += w.z * xv.x; a0.w += w.w * xv.x;
        a1.x += w.x * xv.y; a1.y += w.y * xv.y; a1.z += w.z * xv.y; a1.w += w.w * xv.y;
        a2.x += w.x * xv.z; a2.y += w.y * xv.z; a2.z += w.z * xv.z; a2.w += w.w * xv.z;
        a3.x += w.x * xv.w; a3.y += w.y * xv.w; a3.z += w.z * xv.w; a3.w += w.w * xv.w;
    }

    float4 accs[4] = {a0, a1, a2, a3};
    #pragma unroll
    for (int j = 0; j < 4; ++j) {
        int node = nb + ng * 4 + j;
        *(float4*)&xl[(size_t)node * 128 + og * 4] = accs[j];
        float pl = accs[j].x * attl4.x + accs[j].y * attl4.y +
                   accs[j].z * attl4.z + accs[j].w * attl4.w;
        float pr = accs[j].x * attr4.x + accs[j].y * attr4.y +
                   accs[j].z * attr4.z + accs[j].w * attr4.w;
        #pragma unroll
        for (int off = 1; off <= 4; off <<= 1) {   // reduce 8 og-lanes of one head
            pl += __shfl_xor(pl, off);
            pr += __shfl_xor(pr, off);
        }
        if ((og & 7) == 0) {
            al[(size_t)node * 4 + (og >> 3)] = pl;
            ar[(size_t)node * 4 + (og >> 3)] = pr;
        }
    }
}

// ---- scan: block-level exclusive, top-level over block sums, then add ----
__global__ void k_scan_block(const int* __restrict__ deg, int* __restrict__ row_tmp,
                             int* __restrict__ bsum) {
    __shared__ int sh[256];
    int t = threadIdx.x, i = blockIdx.x * 256 + t;
    int d = (i < NN) ? deg[i] : 0;
    int v = d;
    sh[t] = v; __syncthreads();
    for (int off = 1; off < 256; off <<= 1) {
        int add = (t >= off) ? sh[t - off] : 0;
        __syncthreads();
        v += add; sh[t] = v; __syncthreads();
    }
    if (i < NN) row_tmp[i] = v - d;
    if (t == 255) bsum[blockIdx.x] = v;
}

__global__ void k_scan_top(int* __restrict__ bsum) {
    __shared__ int sh[512];
    int t = threadIdx.x;
    int d = (t < NB) ? bsum[t] : 0;
    int v = d;
    sh[t] = v; __syncthreads();
    for (int off = 1; off < 512; off <<= 1) {
        int add = (t >= off) ? sh[t - off] : 0;
        __syncthreads();
        v += add; sh[t] = v; __syncthreads();
    }
    if (t < NB) bsum[t] = v - d;
}

__global__ void k_scan_add(const int* __restrict__ row_tmp, const int* __restrict__ bsum,
                           int* __restrict__ row, int* __restrict__ cursor) {
    int i = blockIdx.x * 256 + threadIdx.x;
    if (i < NN) {
        int v = row_tmp[i] + bsum[i >> 8];
        row[i] = v;
        cursor[i] = v;
    }
    if (i == 0) row[NN] = NE;
}

// ---- per-edge logits + scatter into dst-sorted CSR slots ----
__global__ __launch_bounds__(256) void k_scatter(
        const float* __restrict__ eattr, const int* __restrict__ ei,
        const float* __restrict__ al, const float* __restrict__ ar,
        const float* __restrict__ we, int* __restrict__ cursor,
        int* __restrict__ csr_src, float* __restrict__ alpha_s) {
    __shared__ __align__(16) float wsh[128];
    if (threadIdx.x < 128) wsh[threadIdx.x] = we[threadIdx.x];
    __syncthreads();
    int e = blockIdx.x * 256 + threadIdx.x;
    int src = ei[e], dst = ei[NE + e];
    const float4* ea = (const float4*)(eattr + (size_t)e * 32);
    float a[4] = {0.f, 0.f, 0.f, 0.f};
    #pragma unroll
    for (int r = 0; r < 8; ++r) {
        float4 v = ea[r];
        #pragma unroll
        for (int h = 0; h < 4; ++h) {
            float4 w = *(const float4*)&wsh[h * 32 + r * 4];
            a[h] += v.x * w.x + v.y * w.y + v.z * w.z + v.w * w.w;
        }
    }
    float4 ls = *(const float4*)&al[(size_t)src * 4];
    float4 rs = *(const float4*)&ar[(size_t)dst * 4];
    a[0] += ls.x + rs.x; a[1] += ls.y + rs.y;
    a[2] += ls.z + rs.z; a[3] += ls.w + rs.w;
    #pragma unroll
    for (int h = 0; h < 4; ++h) a[h] = a[h] > 0.f ? a[h] : NEG * a[h];
    int slot = atomicAdd(&cursor[dst], 1);
    csr_src[slot] = src;
    *(float4*)&alpha_s[(size_t)slot * 4] = make_float4(a[0], a[1], a[2], a[3]);
}

// ---- per-node two-phase softmax + gather-accumulate; one block per node ----
__global__ __launch_bounds__(128) void k_out(
        const int* __restrict__ row, const int* __restrict__ csr_src,
        const float* __restrict__ alpha_s, const float* __restrict__ xl,
        const float* __restrict__ bias, float* __restrict__ out) {
    int n = blockIdx.x;
    int t = threadIdx.x, h = t >> 5;
    int s0 = row[n], s1 = row[n + 1];
    float m = -1e30f;
    for (int s = s0; s < s1; ++s)
        m = fmaxf(m, alpha_s[(size_t)s * 4 + h]);
    float l = 0.f, O = 0.f;
    for (int s = s0; s < s1; ++s) {
        float ex = __expf(alpha_s[(size_t)s * 4 + h] - m);
        l += ex;
        int src = csr_src[s];
        O += ex * xl[(size_t)src * 128 + t];
    }
    out[(size_t)n * 128 + t] = O / (l + 1e-16f) + bias[t];
}

extern "C" void kernel_launch(void* const* d_in, const int* in_sizes, int n_in,
                              void* d_out, int out_size, void* d_ws, size_t ws_size,
                              hipStream_t stream) {
    const float* x     = (const float*)d_in[0];
    const float* eattr = (const float*)d_in[1];
    const float* Wl    = (const float*)d_in[2];
    const float* We    = (const float*)d_in[3];
    const float* att_l = (const float*)d_in[4];
    const float* att_r = (const float*)d_in[5];
    const float* att_e = (const float*)d_in[6];
    const float* bias  = (const float*)d_in[7];
    const int*   ei    = (const int*)d_in[8];
    float* out = (float*)d_out;

    float* ws = (float*)d_ws;
    float* xl      = ws + OFF_XL;
    float* al      = ws + OFF_AL;
    float* ar      = ws + OFF_AR;
    float* we      = ws + OFF_WE;
    float* alpha_s = ws + OFF_ALPHA;
    int*   csr_src = (int*)(ws + OFF_SRC);
    int*   row_tmp = (int*)(ws + OFF_TMP);   // aliases csr_src (dead before scatter)
    int*   bsum    = (int*)(ws + OFF_BSUM);  // aliases csr_src region too
    int*   deg     = (int*)(ws + OFF_DEG);   // becomes cursor after scan
    int*   rowp    = (int*)(ws + OFF_ROW);

    k_prep<<<1, 128, 0, stream>>>(We, att_e, we);
    k_zero<<<NB, 256, 0, stream>>>(deg);
    k_hist<<<NE / 256, 256, 0, stream>>>(ei, deg);
    k_node<<<NN / 32, 256, 0, stream>>>(x, Wl, att_l, att_r, xl, al, ar);
    k_scan_block<<<NB, 256, 0, stream>>>(deg, row_tmp, bsum);
    k_scan_top<<<1, 512, 0, stream>>>(bsum);
    k_scan_add<<<NB, 256, 0, stream>>>(row_tmp, bsum, rowp, deg);
    k_scatter<<<NE / 256, 256, 0, stream>>>(eattr, ei, al, ar, we, deg, csr_src, alpha_s);
    k_out<<<NN, 128, 0, stream>>>(rowp, csr_src, alpha_s, xl, bias, out);
}

// Round 4
// 682.383 us; speedup vs baseline: 2.5899x; 1.1775x over previous
//
#include <hip/hip_runtime.h>

#define NN 100000
#define NE 1600000
#define NB 391            // ceil(NN/256)
#define NEG 0.2f

// workspace layout (4-byte units)
#define OFF_XLB   ((size_t)0)            // NN*128 bf16 (ushort) = 6,400,000 f-units
#define OFF_AL    ((size_t)6400000)      // NN*4 f
#define OFF_AR    ((size_t)6800000)      // NN*4 f
#define OFF_WE    ((size_t)7200000)      // 128 f
#define OFF_ALPHA ((size_t)7200128)      // NE*4 f (dst-sorted)
#define OFF_SRC   ((size_t)13600128)     // NE int (dst-sorted src); TMP/BSUM alias pre-scatter
#define OFF_TMP   OFF_SRC                // NN int (dead before k_scatter writes SRC)
#define OFF_BSUM  (OFF_SRC + 110000)     // 512 int (dead before k_scatter)
#define OFF_DEG   ((size_t)15200128)     // NN int (deg, then cursor)
#define OFF_ROW   ((size_t)15300128)     // NN+1 int
// total ~15,400,129 * 4B = 61.6 MB

__device__ __forceinline__ unsigned short f2bf(float f) {   // RNE
    unsigned u = __float_as_uint(f);
    u += 0x7fffu + ((u >> 16) & 1u);
    return (unsigned short)(u >> 16);
}
__device__ __forceinline__ float bf2f(unsigned short v) {
    return __uint_as_float((unsigned)v << 16);
}

// fold att_e into We (block 0) + zero deg (all blocks)
__global__ void k_prep_zero(const float* __restrict__ We, const float* __restrict__ att_e,
                            float* __restrict__ we, int* __restrict__ deg) {
    int i = blockIdx.x * 256 + threadIdx.x;
    if (i < NN) deg[i] = 0;
    if (blockIdx.x == 0 && threadIdx.x < 128) {
        int t = threadIdx.x, h = t >> 5, k = t & 31;
        float s = 0.f;
        for (int c = 0; c < 32; ++c)
            s += att_e[h * 32 + c] * We[(size_t)(h * 32 + c) * 32 + k];
        we[t] = s;
    }
}

__global__ void k_hist(const int* __restrict__ ei, int* __restrict__ deg) {
    int e = blockIdx.x * 256 + threadIdx.x;
    atomicAdd(&deg[ei[NE + e]], 1);
}

// ---- node projection GEMM: xl = x @ Wl.T (stored bf16), fused al/ar reductions ----
// 32 nodes/block, 256 thr = 32 out-groups x 8 node-groups; thread = 4 outs x 4 nodes.
__global__ __launch_bounds__(256, 2) void k_node(
        const float* __restrict__ x, const float* __restrict__ Wl,
        const float* __restrict__ attl, const float* __restrict__ attr_,
        unsigned short* __restrict__ xlb, float* __restrict__ al, float* __restrict__ ar) {
    __shared__ float wT[128 * 128];   // wT[k*128+o]
    __shared__ float xT[128 * 32];    // xT[k*32+n]
    int t = threadIdx.x;
    int og = t & 31, ng = t >> 5;
    int nb = blockIdx.x * 32;

    {   // stage Wl transposed: 256 thr x 16 float4 = full 128x128 tile
        int o = t & 127, q = t >> 7;              // o 0..127, q 0..1
        #pragma unroll
        for (int chunk = 0; chunk < 16; ++chunk) {
            int k0 = chunk * 8 + q * 4;
            float4 w = *(const float4*)&Wl[(size_t)o * 128 + k0];
            wT[(k0 + 0) * 128 + o] = w.x;
            wT[(k0 + 1) * 128 + o] = w.y;
            wT[(k0 + 2) * 128 + o] = w.z;
            wT[(k0 + 3) * 128 + o] = w.w;
        }
    }
    {   // stage x tile transposed
        int n = t & 31, q = t >> 5;               // q 0..7
        #pragma unroll
        for (int chunk = 0; chunk < 4; ++chunk) {
            int k0 = chunk * 32 + q * 4;
            float4 v = *(const float4*)&x[(size_t)(nb + n) * 128 + k0];
            xT[(k0 + 0) * 32 + n] = v.x;
            xT[(k0 + 1) * 32 + n] = v.y;
            xT[(k0 + 2) * 32 + n] = v.z;
            xT[(k0 + 3) * 32 + n] = v.w;
        }
    }
    float4 attl4 = *(const float4*)&attl[og * 4];
    float4 attr4 = *(const float4*)&attr_[og * 4];
    __syncthreads();

    float4 a0 = make_float4(0,0,0,0), a1 = a0, a2 = a0, a3 = a0;
    #pragma unroll 8
    for (int k = 0; k < 128; ++k) {
        float4 w  = *(const float4*)&wT[k * 128 + og * 4];
        float4 xv = *(const float4*)&xT[k * 32  + ng * 4];
        a0.x += w.x * xv.x; a0.y += w.y * xv.x; a0.z += w.z * xv.x; a0.w += w.w * xv.x;
        a1.x += w.x * xv.y; a1.y += w.y * xv.y; a1.z += w.z * xv.y; a1.w += w.w * xv.y;
        a2.x += w.x * xv.z; a2.y += w.y * xv.z; a2.z += w.z * xv.z; a2.w += w.w * xv.z;
        a3.x += w.x * xv.w; a3.y += w.y * xv.w; a3.z += w.z * xv.w; a3.w += w.w * xv.w;
    }

    float4 accs[4] = {a0, a1, a2, a3};
    #pragma unroll
    for (int j = 0; j < 4; ++j) {
        int node = nb + ng * 4 + j;
        ushort4 pk;
        pk.x = f2bf(accs[j].x); pk.y = f2bf(accs[j].y);
        pk.z = f2bf(accs[j].z); pk.w = f2bf(accs[j].w);
        *(ushort4*)&xlb[(size_t)node * 128 + og * 4] = pk;
        float pl = accs[j].x * attl4.x + accs[j].y * attl4.y +
                   accs[j].z * attl4.z + accs[j].w * attl4.w;
        float pr = accs[j].x * attr4.x + accs[j].y * attr4.y +
                   accs[j].z * attr4.z + accs[j].w * attr4.w;
        #pragma unroll
        for (int off = 1; off <= 4; off <<= 1) {   // reduce 8 og-lanes of one head
            pl += __shfl_xor(pl, off);
            pr += __shfl_xor(pr, off);
        }
        if ((og & 7) == 0) {
            al[(size_t)node * 4 + (og >> 3)] = pl;
            ar[(size_t)node * 4 + (og >> 3)] = pr;
        }
    }
}

// ---- scan: block-level exclusive, top-level over block sums, then add ----
__global__ void k_scan_block(const int* __restrict__ deg, int* __restrict__ row_tmp,
                             int* __restrict__ bsum) {
    __shared__ int sh[256];
    int t = threadIdx.x, i = blockIdx.x * 256 + t;
    int d = (i < NN) ? deg[i] : 0;
    int v = d;
    sh[t] = v; __syncthreads();
    for (int off = 1; off < 256; off <<= 1) {
        int add = (t >= off) ? sh[t - off] : 0;
        __syncthreads();
        v += add; sh[t] = v; __syncthreads();
    }
    if (i < NN) row_tmp[i] = v - d;
    if (t == 255) bsum[blockIdx.x] = v;
}

__global__ void k_scan_top(int* __restrict__ bsum) {
    __shared__ int sh[512];
    int t = threadIdx.x;
    int d = (t < NB) ? bsum[t] : 0;
    int v = d;
    sh[t] = v; __syncthreads();
    for (int off = 1; off < 512; off <<= 1) {
        int add = (t >= off) ? sh[t - off] : 0;
        __syncthreads();
        v += add; sh[t] = v; __syncthreads();
    }
    if (t < NB) bsum[t] = v - d;
}

__global__ void k_scan_add(const int* __restrict__ row_tmp, const int* __restrict__ bsum,
                           int* __restrict__ row, int* __restrict__ cursor) {
    int i = blockIdx.x * 256 + threadIdx.x;
    if (i < NN) {
        int v = row_tmp[i] + bsum[i >> 8];
        row[i] = v;
        cursor[i] = v;
    }
    if (i == 0) row[NN] = NE;
}

// ---- per-edge logits + scatter into dst-sorted CSR slots ----
__global__ __launch_bounds__(256) void k_scatter(
        const float* __restrict__ eattr, const int* __restrict__ ei,
        const float* __restrict__ al, const float* __restrict__ ar,
        const float* __restrict__ we, int* __restrict__ cursor,
        int* __restrict__ csr_src, float* __restrict__ alpha_s) {
    __shared__ __align__(16) float wsh[128];
    if (threadIdx.x < 128) wsh[threadIdx.x] = we[threadIdx.x];
    __syncthreads();
    int e = blockIdx.x * 256 + threadIdx.x;
    int src = ei[e], dst = ei[NE + e];
    const float4* ea = (const float4*)(eattr + (size_t)e * 32);
    float a[4] = {0.f, 0.f, 0.f, 0.f};
    #pragma unroll
    for (int r = 0; r < 8; ++r) {
        float4 v = ea[r];
        #pragma unroll
        for (int h = 0; h < 4; ++h) {
            float4 w = *(const float4*)&wsh[h * 32 + r * 4];
            a[h] += v.x * w.x + v.y * w.y + v.z * w.z + v.w * w.w;
        }
    }
    float4 ls = *(const float4*)&al[(size_t)src * 4];
    float4 rs = *(const float4*)&ar[(size_t)dst * 4];
    a[0] += ls.x + rs.x; a[1] += ls.y + rs.y;
    a[2] += ls.z + rs.z; a[3] += ls.w + rs.w;
    #pragma unroll
    for (int h = 0; h < 4; ++h) a[h] = a[h] > 0.f ? a[h] : NEG * a[h];
    int slot = atomicAdd(&cursor[dst], 1);
    csr_src[slot] = src;
    *(float4*)&alpha_s[(size_t)slot * 4] = make_float4(a[0], a[1], a[2], a[3]);
}

// ---- per-node two-phase softmax + gather-accumulate; one block per node ----
// 4-way edge unrolling: 4 independent (O,l) accumulators keep 4 rows in flight.
__global__ __launch_bounds__(128) void k_out(
        const int* __restrict__ row, const int* __restrict__ csr_src,
        const float* __restrict__ alpha_s, const unsigned short* __restrict__ xlb,
        const float* __restrict__ bias, float* __restrict__ out) {
    int n = blockIdx.x;
    int t = threadIdx.x, h = t >> 5;
    int s0 = row[n], s1 = row[n + 1];

    float m0 = -1e30f, m1 = -1e30f, m2 = -1e30f, m3 = -1e30f;
    int s = s0;
    for (; s + 4 <= s1; s += 4) {
        m0 = fmaxf(m0, alpha_s[(size_t)(s + 0) * 4 + h]);
        m1 = fmaxf(m1, alpha_s[(size_t)(s + 1) * 4 + h]);
        m2 = fmaxf(m2, alpha_s[(size_t)(s + 2) * 4 + h]);
        m3 = fmaxf(m3, alpha_s[(size_t)(s + 3) * 4 + h]);
    }
    for (; s < s1; ++s) m0 = fmaxf(m0, alpha_s[(size_t)s * 4 + h]);
    float m = fmaxf(fmaxf(m0, m1), fmaxf(m2, m3));

    float l0 = 0.f, l1 = 0.f, l2 = 0.f, l3 = 0.f;
    float O0 = 0.f, O1 = 0.f, O2 = 0.f, O3 = 0.f;
    s = s0;
    for (; s + 4 <= s1; s += 4) {
        int src0 = csr_src[s + 0], src1 = csr_src[s + 1];
        int src2 = csr_src[s + 2], src3 = csr_src[s + 3];
        float a0 = alpha_s[(size_t)(s + 0) * 4 + h];
        float a1 = alpha_s[(size_t)(s + 1) * 4 + h];
        float a2 = alpha_s[(size_t)(s + 2) * 4 + h];
        float a3 = alpha_s[(size_t)(s + 3) * 4 + h];
        unsigned short v0 = xlb[(size_t)src0 * 128 + t];
        unsigned short v1 = xlb[(size_t)src1 * 128 + t];
        unsigned short v2 = xlb[(size_t)src2 * 128 + t];
        unsigned short v3 = xlb[(size_t)src3 * 128 + t];
        float e0 = __expf(a0 - m), e1 = __expf(a1 - m);
        float e2 = __expf(a2 - m), e3 = __expf(a3 - m);
        l0 += e0; l1 += e1; l2 += e2; l3 += e3;
        O0 += e0 * bf2f(v0); O1 += e1 * bf2f(v1);
        O2 += e2 * bf2f(v2); O3 += e3 * bf2f(v3);
    }
    for (; s < s1; ++s) {
        float a = alpha_s[(size_t)s * 4 + h];
        unsigned short v = xlb[(size_t)csr_src[s] * 128 + t];
        float e = __expf(a - m);
        l0 += e; O0 += e * bf2f(v);
    }
    float l = (l0 + l1) + (l2 + l3);
    float O = (O0 + O1) + (O2 + O3);
    out[(size_t)n * 128 + t] = O / (l + 1e-16f) + bias[t];
}

extern "C" void kernel_launch(void* const* d_in, const int* in_sizes, int n_in,
                              void* d_out, int out_size, void* d_ws, size_t ws_size,
                              hipStream_t stream) {
    const float* x     = (const float*)d_in[0];
    const float* eattr = (const float*)d_in[1];
    const float* Wl    = (const float*)d_in[2];
    const float* We    = (const float*)d_in[3];
    const float* att_l = (const float*)d_in[4];
    const float* att_r = (const float*)d_in[5];
    const float* att_e = (const float*)d_in[6];
    const float* bias  = (const float*)d_in[7];
    const int*   ei    = (const int*)d_in[8];
    float* out = (float*)d_out;

    float* ws = (float*)d_ws;
    unsigned short* xlb = (unsigned short*)(ws + OFF_XLB);
    float* al      = ws + OFF_AL;
    float* ar      = ws + OFF_AR;
    float* we      = ws + OFF_WE;
    float* alpha_s = ws + OFF_ALPHA;
    int*   csr_src = (int*)(ws + OFF_SRC);
    int*   row_tmp = (int*)(ws + OFF_TMP);
    int*   bsum    = (int*)(ws + OFF_BSUM);
    int*   deg     = (int*)(ws + OFF_DEG);   // becomes cursor after scan
    int*   rowp    = (int*)(ws + OFF_ROW);

    k_prep_zero<<<NB, 256, 0, stream>>>(We, att_e, we, deg);
    k_hist<<<NE / 256, 256, 0, stream>>>(ei, deg);
    k_node<<<NN / 32, 256, 0, stream>>>(x, Wl, att_l, att_r, xlb, al, ar);
    k_scan_block<<<NB, 256, 0, stream>>>(deg, row_tmp, bsum);
    k_scan_top<<<1, 512, 0, stream>>>(bsum);
    k_scan_add<<<NB, 256, 0, stream>>>(row_tmp, bsum, rowp, deg);
    k_scatter<<<NE / 256, 256, 0, stream>>>(eattr, ei, al, ar, we, deg, csr_src, alpha_s);
    k_out<<<NN, 128, 0, stream>>>(rowp, csr_src, alpha_s, xlb, bias, out);
}